// Round 4
// baseline (303.941 us; speedup 1.0000x reference)
//
#include <hip/hip_runtime.h>
#include <hip/hip_bf16.h>
#include <stdint.h>

// ---------- types ----------
typedef __bf16 bf16x8 __attribute__((ext_vector_type(8)));
typedef float  f32x4  __attribute__((ext_vector_type(4)));
typedef unsigned int u32x4 __attribute__((ext_vector_type(4)));

__device__ __forceinline__ unsigned short f2bf(float x) {
    union { float f; unsigned u; } v; v.f = x;
    unsigned r = v.u + 0x7fffu + ((v.u >> 16) & 1u);   // RNE
    return (unsigned short)(r >> 16);
}

__device__ __forceinline__ void async16(const void* g, void* l) {
    __builtin_amdgcn_global_load_lds(
        (const __attribute__((address_space(1))) void*)g,
        (__attribute__((address_space(3))) void*)l,
        16, 0, 0);
}

// ---------- bf16 B^T GEMM, 128x256 block tile, BK=32, 4 waves (64x128 each) ----------
// A: M x K (row-major bf16 bits, lda), Bt: N x K (row-major, ldb)
// C[m][n] = scale * sum_k A[m][k] * Bt[n][k]
// Wave tile 64x128 -> FLOP per LDS-byte 43.7 (vs 32 at 64x64): LDS-BW ceiling lifted.
// K-chunk slots XOR-swizzled on the global-fetch side (bank-conflict-free reads).
template <typename OutT, bool CAUSAL_SKIP, bool KLIMIT>
__global__ __launch_bounds__(256, 2) void gemm_bt(
    const unsigned short* __restrict__ A,
    const unsigned short* __restrict__ Bt,
    OutT* __restrict__ C,
    int M, int N, int K, int lda, int ldb, int ldc,
    long long sA, long long sB, long long sC, float scale)
{
    const int bn = blockIdx.x, bm = blockIdx.y, bz = blockIdx.z;
    if (CAUSAL_SKIP && 2 * bn > bm) return;   // block cols n0 > m0+127 are fully masked

    A  += (long long)bz * sA;
    Bt += (long long)bz * sB;
    C  += (long long)bz * sC;

    const int m0 = bm * 128, n0 = bn * 256;
    const int Keff = KLIMIT ? min(K, (bm + 1) * 128) : K;

    __shared__ __align__(16) unsigned short LDS[(128 + 256) * 32];  // 24 KB
    unsigned short* As = LDS;                 // 128 x 32
    unsigned short* Bs = LDS + 128 * 32;      // 256 x 32

    const int tid  = threadIdx.x;
    const int w    = tid >> 6, l = tid & 63;
    const int wr   = w >> 1,  wc = w & 1;     // wave grid 2x2: rows 64*wr, cols 128*wc
    const int lrow = l & 15,  quad = l >> 4;

    f32x4 acc[4][8] = {};

    // staging: chunk = 16 rows x 32 cols = 512 elems, one async16 per lane.
    // physical k-slot l&3 holds logical chunk (l&3)^((l>>3)&3) (row-pair swizzle).
    const int rA   = 32 * w + (l >> 2);       // A rows 32w .. 32w+31 (2 chunks)
    const int rB   = 64 * w + (l >> 2);       // B rows 64w .. 64w+63 (4 chunks)
    const int cOff = (((l & 3) ^ ((l >> 3) & 3))) * 8;
    const unsigned short* aG0 = A  + (long long)(m0 + rA)      * lda + cOff;
    const unsigned short* aG1 = A  + (long long)(m0 + rA + 16) * lda + cOff;
    const unsigned short* bG0 = Bt + (long long)(n0 + rB)      * ldb + cOff;
    const unsigned short* bG1 = Bt + (long long)(n0 + rB + 16) * ldb + cOff;
    const unsigned short* bG2 = Bt + (long long)(n0 + rB + 32) * ldb + cOff;
    const unsigned short* bG3 = Bt + (long long)(n0 + rB + 48) * ldb + cOff;
    unsigned short* aL0 = &As[(2 * w) * 512 + l * 8];
    unsigned short* aL1 = aL0 + 512;
    unsigned short* bL0 = &Bs[(4 * w) * 512 + l * 8];
    unsigned short* bL1 = bL0 + 512;
    unsigned short* bL2 = bL0 + 1024;
    unsigned short* bL3 = bL0 + 1536;

    const int sl = (lrow >> 1) & 3;           // un-swizzle for fragment reads

    for (int k0 = 0; k0 < Keff; k0 += 32) {
        async16(aG0 + k0, aL0);
        async16(aG1 + k0, aL1);
        async16(bG0 + k0, bL0);
        async16(bG1 + k0, bL1);
        async16(bG2 + k0, bL2);
        async16(bG3 + k0, bL3);
        __syncthreads();

        bf16x8 bfr[8];
#pragma unroll
        for (int j = 0; j < 8; j++)
            bfr[j] = *(const bf16x8*)&Bs[(wc * 128 + j * 16 + lrow) * 32 + (quad ^ sl) * 8];
#pragma unroll
        for (int i = 0; i < 4; i++) {
            bf16x8 af = *(const bf16x8*)&As[(wr * 64 + i * 16 + lrow) * 32 + (quad ^ sl) * 8];
#pragma unroll
            for (int j = 0; j < 8; j++)
                acc[i][j] = __builtin_amdgcn_mfma_f32_16x16x32_bf16(af, bfr[j], acc[i][j], 0, 0, 0);
        }
        __syncthreads();
    }

    // ---- epilogue: per-wave LDS repack (region 16 rows x 144 B) -> wide stores ----
    char* eb = (char*)LDS + w * 2304;
    const int erow = l >> 2, ep = l & 3;

    if constexpr (sizeof(OutT) == 2) {
#pragma unroll
        for (int i = 0; i < 4; i++) {
            const long long gm = m0 + wr * 64 + i * 16 + erow;
#pragma unroll
            for (int h = 0; h < 2; h++) {     // 64-col halves
#pragma unroll
                for (int jj = 0; jj < 4; jj++)
#pragma unroll
                    for (int r = 0; r < 4; r++)
                        *(unsigned short*)(eb + (quad * 4 + r) * 144 + (jj * 16 + lrow) * 2) =
                            f2bf(acc[i][h * 4 + jj][r] * scale);
#pragma unroll
                for (int c = 0; c < 2; c++) {
                    u32x4 d = *(u32x4*)(eb + erow * 144 + ep * 32 + c * 16);
                    *(u32x4*)((unsigned short*)C + gm * ldc +
                              (n0 + wc * 128 + h * 64 + ep * 16 + c * 8)) = d;
                }
            }
        }
    } else {
#pragma unroll
        for (int i = 0; i < 4; i++) {
            const long long gm = m0 + wr * 64 + i * 16 + erow;
#pragma unroll
            for (int jc = 0; jc < 4; jc++) {  // 32-col quarters
#pragma unroll
                for (int jj = 0; jj < 2; jj++)
#pragma unroll
                    for (int r = 0; r < 4; r++)
                        *(float*)(eb + (quad * 4 + r) * 144 + (jj * 16 + lrow) * 4) =
                            acc[i][jc * 2 + jj][r] * scale;
#pragma unroll
                for (int c = 0; c < 2; c++) {
                    f32x4 d = *(f32x4*)(eb + erow * 144 + ep * 32 + c * 16);
                    *(f32x4*)((float*)C + gm * ldc +
                              (n0 + wc * 128 + jc * 32 + ep * 8 + c * 4)) = d;
                }
            }
        }
    }
}

// ---------- fp32 -> bf16 cast (vectorized) ----------
__global__ __launch_bounds__(256) void cast_f32_bf16(
    const float4* __restrict__ in, unsigned short* __restrict__ out, int n4)
{
    int i = blockIdx.x * 256 + threadIdx.x;
    if (i >= n4) return;
    float4 v = in[i];
    union { unsigned short u[4]; uint2 p; } o;
    o.u[0] = f2bf(v.x); o.u[1] = f2bf(v.y); o.u[2] = f2bf(v.z); o.u[3] = f2bf(v.w);
    *(uint2*)(out + (long long)i * 4) = o.p;
}

// ---------- fused W_{q,k,v} (1024x1024 fp32) -> concatenated W^T (3072 x 1024 bf16) ----------
__global__ __launch_bounds__(256) void transpose_cast_w3(
    const float* __restrict__ W0, const float* __restrict__ W1,
    const float* __restrict__ W2, unsigned short* __restrict__ out, int n)
{
    const float* in = (blockIdx.z == 0) ? W0 : (blockIdx.z == 1) ? W1 : W2;
    out += (long long)blockIdx.z * n * n;
    __shared__ float tile[32][33];
    const int tx = threadIdx.x, ty = threadIdx.y;
    const int c0 = blockIdx.x * 32, r0 = blockIdx.y * 32;
#pragma unroll
    for (int i = 0; i < 4; i++)
        tile[ty + i * 8][tx] = in[(long long)(r0 + ty + i * 8) * n + c0 + tx];
    __syncthreads();
#pragma unroll
    for (int i = 0; i < 4; i++)
        out[(long long)(c0 + ty + i * 8) * n + r0 + tx] = f2bf(tile[tx][ty + i * 8]);
}

// ---------- bf16 strided transpose, batched over z: out[c][r] = in[r][c] ----------
__global__ __launch_bounds__(256) void transpose_bf16_k(
    const unsigned short* __restrict__ in, unsigned short* __restrict__ out,
    int ldin, int ldout, long long sin, long long sout)
{
    in  += (long long)blockIdx.z * sin;
    out += (long long)blockIdx.z * sout;
    __shared__ unsigned short tile[32][33];
    const int tx = threadIdx.x, ty = threadIdx.y;
    const int c0 = blockIdx.x * 32, r0 = blockIdx.y * 32;
#pragma unroll
    for (int i = 0; i < 4; i++)
        tile[ty + i * 8][tx] = in[(long long)(r0 + ty + i * 8) * ldin + c0 + tx];
    __syncthreads();
#pragma unroll
    for (int i = 0; i < 4; i++)
        out[(long long)(c0 + ty + i * 8) * ldout + r0 + tx] = tile[tx][ty + i * 8];
}

// ---------- causal softmax: S (fp32, B*T rows of T) -> P (bf16) ----------
__global__ __launch_bounds__(256) void causal_softmax(
    const float* __restrict__ S, unsigned short* __restrict__ P, int T)
{
    const int row = blockIdx.x;            // 0 .. B*T-1
    const int t   = row & (T - 1);
    const float* s = S + (long long)row * T;
    unsigned short* p = P + (long long)row * T;
    const int L = t + 1;
    const int tid = threadIdx.x;

    float v[8];
    float mx = -3.0e38f;
#pragma unroll
    for (int k = 0; k < 8; k++) {
        const int j = tid + k * 256;
        v[k] = (j < L) ? s[j] : -3.0e38f;
        mx = fmaxf(mx, v[k]);
    }
#pragma unroll
    for (int off = 32; off; off >>= 1) mx = fmaxf(mx, __shfl_xor(mx, off));
    __shared__ float red[4], red2[4];
    const int wid = tid >> 6, lid = tid & 63;
    if (lid == 0) red[wid] = mx;
    __syncthreads();
    mx = fmaxf(fmaxf(red[0], red[1]), fmaxf(red[2], red[3]));

    float sum = 0.f;
#pragma unroll
    for (int k = 0; k < 8; k++) { v[k] = __expf(v[k] - mx); sum += v[k]; }
#pragma unroll
    for (int off = 32; off; off >>= 1) sum += __shfl_xor(sum, off);
    if (lid == 0) red2[wid] = sum;
    __syncthreads();
    sum = red2[0] + red2[1] + red2[2] + red2[3];
    const float inv = 1.0f / sum;
#pragma unroll
    for (int k = 0; k < 8; k++) {
        const int j = tid + k * 256;
        p[j] = f2bf(v[k] * inv);          // exp(-huge)=0 for masked lanes
    }
}

// ---------- launch ----------
extern "C" void kernel_launch(void* const* d_in, const int* in_sizes, int n_in,
                              void* d_out, int out_size, void* d_ws, size_t ws_size,
                              hipStream_t stream)
{
    const int B = 4, T = 2048, C = 1024, D = 1024;
    const float* x  = (const float*)d_in[0];
    const float* Wq = (const float*)d_in[1];
    const float* Wk = (const float*)d_in[2];
    const float* Wv = (const float*)d_in[3];
    float* out = (float*)d_out;
    char* ws = (char*)d_ws;

    const size_t MB = 1ull << 20;
    // layout (peak 150 MB):
    //  0..16   Xbf        [dead after QKV gemm]
    // 16..22   WqkvT      [dead after QKV gemm]
    // 22..70   QKV (4 x 2048 x 3072 bf16)   [dead after Vt + S]
    // 70..86   Vt  (4 x 1024 x 2048 bf16)
    // 86..150  S   (4 x 2048 x 2048 fp32)
    //  0..32   P   (4 x 2048 x 2048 bf16)   [overlays dead Xbf/WqkvT/QKV-head]
    unsigned short* Xbf   = (unsigned short*)(ws + 0);
    unsigned short* WqkvT = (unsigned short*)(ws + 16 * MB);
    unsigned short* QKV   = (unsigned short*)(ws + 22 * MB);
    unsigned short* Vt    = (unsigned short*)(ws + 70 * MB);
    float*          S     = (float*)(ws + 86 * MB);
    unsigned short* P     = (unsigned short*)(ws + 0);

    const long long sX   = (long long)T * C;
    const long long sQKV = (long long)T * 3 * D;
    const long long sVt  = (long long)D * T;
    const long long sS   = (long long)T * T;
    const long long sO   = (long long)T * D;

    // 1) x -> bf16
    {
        int n4 = B * T * C / 4;
        cast_f32_bf16<<<dim3((n4 + 255) / 256), dim3(256), 0, stream>>>(
            (const float4*)x, Xbf, n4);
    }
    // 2) fused W^T cast
    {
        dim3 g(32, 32, 3), b(32, 8);
        transpose_cast_w3<<<g, b, 0, stream>>>(Wq, Wk, Wv, WqkvT, 1024);
    }
    // 3) fused QKV GEMM: per batch M=2048, N=3072, K=1024 (128x256 tiles)
    {
        dim3 g(3072 / 256, 2048 / 128, 4), b(256);
        gemm_bt<unsigned short, false, false><<<g, b, 0, stream>>>(
            Xbf, WqkvT, QKV, 2048, 3072, 1024, 1024, 1024, 3072, sX, 0, sQKV, 1.0f);
    }
    // 4) V (cols 2048..3071 of QKV) -> V^T
    {
        dim3 g(1024 / 32, 2048 / 32, 4), b(32, 8);
        transpose_bf16_k<<<g, b, 0, stream>>>(
            QKV + 2 * D, Vt, 3 * D, T, sQKV, sVt);
    }
    // 5) S = Q K^T / 32, causal lower blocks only
    {
        dim3 g(2048 / 256, 2048 / 128, 4), b(256);
        gemm_bt<float, true, false><<<g, b, 0, stream>>>(
            QKV, QKV + D, S, 2048, 2048, 1024, 3 * D, 3 * D, 2048, sQKV, sQKV, sS, 0.03125f);
    }
    // 6) causal softmax -> P (bf16)
    {
        causal_softmax<<<dim3(B * T), dim3(256), 0, stream>>>(S, P, T);
    }
    // 7) O = P V (K clamped causally per row-block), fp32 out
    {
        dim3 g(1024 / 256, 2048 / 128, 4), b(256);
        gemm_bt<float, false, true><<<g, b, 0, stream>>>(
            P, Vt, out, 2048, 1024, 2048, 2048, 2048, 1024, sS, sVt, sO, 1.0f);
    }
    (void)in_sizes; (void)n_in; (void)out_size; (void)ws_size;
}

// Round 5
// 263.189 us; speedup vs baseline: 1.1548x; 1.1548x over previous
//
#include <hip/hip_runtime.h>
#include <hip/hip_bf16.h>
#include <stdint.h>

// ---------- types ----------
typedef __bf16 bf16x8 __attribute__((ext_vector_type(8)));
typedef float  f32x4  __attribute__((ext_vector_type(4)));
typedef unsigned int u32x4 __attribute__((ext_vector_type(4)));

__device__ __forceinline__ unsigned short f2bf(float x) {
    union { float f; unsigned u; } v; v.f = x;
    unsigned r = v.u + 0x7fffu + ((v.u >> 16) & 1u);   // RNE
    return (unsigned short)(r >> 16);
}

__device__ __forceinline__ void async16(const void* g, void* l) {
    __builtin_amdgcn_global_load_lds(
        (const __attribute__((address_space(1))) void*)g,
        (__attribute__((address_space(3))) void*)l,
        16, 0, 0);
}

// ---------- bf16 B^T GEMM, 128x128 tile, BK=32, 4 waves, DOUBLE-BUFFERED ----------
// A: M x K (row-major bf16 bits, lda), Bt: N x K (row-major, ldb)
// C[m][n] = scale * sum_k A[m][k] * Bt[n][k]
// Prefetch-after-barrier: tile k+1 staged into alternate 16 KB buffer while
// MFMA consumes tile k; the next barrier's vmcnt drain covers loads issued a
// full compute-phase earlier (latency hidden). K-chunk slots XOR-swizzled on
// the global-fetch side -> bank-conflict-free fragment reads.
template <typename OutT, bool CAUSAL_SKIP, bool KLIMIT>
__global__ __launch_bounds__(256, 3) void gemm_bt(
    const unsigned short* __restrict__ A,
    const unsigned short* __restrict__ Bt,
    OutT* __restrict__ C,
    int M, int N, int K, int lda, int ldb, int ldc,
    long long sA, long long sB, long long sC, float scale)
{
    const int bn = blockIdx.x, bm = blockIdx.y, bz = blockIdx.z;
    if (CAUSAL_SKIP && bn > bm) return;

    A  += (long long)bz * sA;
    Bt += (long long)bz * sB;
    C  += (long long)bz * sC;

    const int m0 = bm * 128, n0 = bn * 128;
    const int Keff = KLIMIT ? min(K, (bm + 1) * 128) : K;

    // [buf][A:128x32 | B:128x32], 16 KB per buffer
    __shared__ __align__(16) unsigned short LDS[2 * 2 * 128 * 32];

    const int tid  = threadIdx.x;
    const int w    = tid >> 6, l = tid & 63;
    const int wr   = w >> 1,  wc = w & 1;
    const int lrow = l & 15,  quad = l >> 4;

    f32x4 acc[4][4] = {};

    // staging: lane l of chunk c covers row 16c + (l>>2); physical k-slot l&3
    // holds logical chunk (l&3)^((l>>3)&3) (row-pair swizzle).
    const int rA0  = 32 * w + (l >> 2);
    const int cOff = (((l & 3) ^ ((l >> 3) & 3))) * 8;
    const unsigned short* aG0 = A  + (long long)(m0 + rA0)      * lda + cOff;
    const unsigned short* aG1 = A  + (long long)(m0 + rA0 + 16) * lda + cOff;
    const unsigned short* bG0 = Bt + (long long)(n0 + rA0)      * ldb + cOff;
    const unsigned short* bG1 = Bt + (long long)(n0 + rA0 + 16) * ldb + cOff;
    unsigned short* aL = &LDS[(2 * w) * 512 + l * 8];           // A region of buf0
    unsigned short* bL = aL + 4096;                             // B region of buf0

    const int sl = (lrow >> 1) & 3;   // un-swizzle for fragment reads

    // prologue: stage tile 0 into buf 0
    async16(aG0, aL);
    async16(aG1, aL + 512);
    async16(bG0, bL);
    async16(bG1, bL + 512);

    for (int k0 = 0; k0 < Keff; k0 += 32) {
        const int cur = ((k0 >> 5) & 1) * 8192;   // element offset of current buf
        __syncthreads();                          // tile k0 ready in cur

        if (k0 + 32 < Keff) {                     // prefetch tile k0+32 into other buf
            const int nxt = cur ^ 8192;
            async16(aG0 + k0 + 32, aL + nxt);
            async16(aG1 + k0 + 32, aL + nxt + 512);
            async16(bG0 + k0 + 32, bL + nxt);
            async16(bG1 + k0 + 32, bL + nxt + 512);
        }

        const unsigned short* As = &LDS[cur];
        const unsigned short* Bs = &LDS[cur + 4096];
        bf16x8 af[4], bfr[4];
#pragma unroll
        for (int i = 0; i < 4; i++) {
            af[i]  = *(const bf16x8*)&As[(wr * 64 + i * 16 + lrow) * 32 + (quad ^ sl) * 8];
            bfr[i] = *(const bf16x8*)&Bs[(wc * 64 + i * 16 + lrow) * 32 + (quad ^ sl) * 8];
        }
#pragma unroll
        for (int i = 0; i < 4; i++)
#pragma unroll
            for (int j = 0; j < 4; j++)
                acc[i][j] = __builtin_amdgcn_mfma_f32_16x16x32_bf16(af[i], bfr[j], acc[i][j], 0, 0, 0);
    }
    __syncthreads();   // all waves done computing before LDS is reused for repack

    // ---- epilogue: per-wave LDS repack (16 rows x 144 B stride, 2288 B/wave) ----
    char* eb = (char*)LDS + w * 2288;
    const int erow = l >> 2, ep = l & 3;

    if constexpr (sizeof(OutT) == 2) {
#pragma unroll
        for (int i = 0; i < 4; i++) {
#pragma unroll
            for (int j = 0; j < 4; j++)
#pragma unroll
                for (int r = 0; r < 4; r++)
                    *(unsigned short*)(eb + (quad * 4 + r) * 144 + (j * 16 + lrow) * 2) =
                        f2bf(acc[i][j][r] * scale);
            const long long gm = m0 + wr * 64 + i * 16 + erow;
#pragma unroll
            for (int c = 0; c < 2; c++) {
                u32x4 d = *(u32x4*)(eb + erow * 144 + ep * 32 + c * 16);
                *(u32x4*)((unsigned short*)C + gm * ldc + (n0 + wc * 64 + ep * 16 + c * 8)) = d;
            }
        }
    } else {
#pragma unroll
        for (int i = 0; i < 4; i++) {
            const long long gm = m0 + wr * 64 + i * 16 + erow;
#pragma unroll
            for (int jc = 0; jc < 2; jc++) {
#pragma unroll
                for (int jj = 0; jj < 2; jj++)
#pragma unroll
                    for (int r = 0; r < 4; r++)
                        *(float*)(eb + (quad * 4 + r) * 144 + (jj * 16 + lrow) * 4) =
                            acc[i][2 * jc + jj][r] * scale;
#pragma unroll
                for (int c = 0; c < 2; c++) {
                    f32x4 d = *(f32x4*)(eb + erow * 144 + ep * 32 + c * 16);
                    *(f32x4*)((float*)C + gm * ldc + (n0 + wc * 64 + jc * 32 + ep * 8 + c * 4)) = d;
                }
            }
        }
    }
}

// ---------- fp32 -> bf16 cast (vectorized) ----------
__global__ __launch_bounds__(256) void cast_f32_bf16(
    const float4* __restrict__ in, unsigned short* __restrict__ out, int n4)
{
    int i = blockIdx.x * 256 + threadIdx.x;
    if (i >= n4) return;
    float4 v = in[i];
    union { unsigned short u[4]; uint2 p; } o;
    o.u[0] = f2bf(v.x); o.u[1] = f2bf(v.y); o.u[2] = f2bf(v.z); o.u[3] = f2bf(v.w);
    *(uint2*)(out + (long long)i * 4) = o.p;
}

// ---------- fused W_{q,k,v} (1024x1024 fp32) -> concatenated W^T (3072 x 1024 bf16) ----------
__global__ __launch_bounds__(256) void transpose_cast_w3(
    const float* __restrict__ W0, const float* __restrict__ W1,
    const float* __restrict__ W2, unsigned short* __restrict__ out, int n)
{
    const float* in = (blockIdx.z == 0) ? W0 : (blockIdx.z == 1) ? W1 : W2;
    out += (long long)blockIdx.z * n * n;
    __shared__ float tile[32][33];
    const int tx = threadIdx.x, ty = threadIdx.y;
    const int c0 = blockIdx.x * 32, r0 = blockIdx.y * 32;
#pragma unroll
    for (int i = 0; i < 4; i++)
        tile[ty + i * 8][tx] = in[(long long)(r0 + ty + i * 8) * n + c0 + tx];
    __syncthreads();
#pragma unroll
    for (int i = 0; i < 4; i++)
        out[(long long)(c0 + ty + i * 8) * n + r0 + tx] = f2bf(tile[tx][ty + i * 8]);
}

// ---------- bf16 strided transpose, batched over z: out[c][r] = in[r][c] ----------
__global__ __launch_bounds__(256) void transpose_bf16_k(
    const unsigned short* __restrict__ in, unsigned short* __restrict__ out,
    int ldin, int ldout, long long sin, long long sout)
{
    in  += (long long)blockIdx.z * sin;
    out += (long long)blockIdx.z * sout;
    __shared__ unsigned short tile[32][33];
    const int tx = threadIdx.x, ty = threadIdx.y;
    const int c0 = blockIdx.x * 32, r0 = blockIdx.y * 32;
#pragma unroll
    for (int i = 0; i < 4; i++)
        tile[ty + i * 8][tx] = in[(long long)(r0 + ty + i * 8) * ldin + c0 + tx];
    __syncthreads();
#pragma unroll
    for (int i = 0; i < 4; i++)
        out[(long long)(c0 + ty + i * 8) * ldout + r0 + tx] = tile[tx][ty + i * 8];
}

// ---------- causal softmax: S (fp32, B*T rows of T) -> P (bf16) ----------
__global__ __launch_bounds__(256) void causal_softmax(
    const float* __restrict__ S, unsigned short* __restrict__ P, int T)
{
    const int row = blockIdx.x;            // 0 .. B*T-1
    const int t   = row & (T - 1);
    const float* s = S + (long long)row * T;
    unsigned short* p = P + (long long)row * T;
    const int L = t + 1;
    const int tid = threadIdx.x;

    float v[8];
    float mx = -3.0e38f;
#pragma unroll
    for (int k = 0; k < 8; k++) {
        const int j = tid + k * 256;
        v[k] = (j < L) ? s[j] : -3.0e38f;
        mx = fmaxf(mx, v[k]);
    }
#pragma unroll
    for (int off = 32; off; off >>= 1) mx = fmaxf(mx, __shfl_xor(mx, off));
    __shared__ float red[4], red2[4];
    const int wid = tid >> 6, lid = tid & 63;
    if (lid == 0) red[wid] = mx;
    __syncthreads();
    mx = fmaxf(fmaxf(red[0], red[1]), fmaxf(red[2], red[3]));

    float sum = 0.f;
#pragma unroll
    for (int k = 0; k < 8; k++) { v[k] = __expf(v[k] - mx); sum += v[k]; }
#pragma unroll
    for (int off = 32; off; off >>= 1) sum += __shfl_xor(sum, off);
    if (lid == 0) red2[wid] = sum;
    __syncthreads();
    sum = red2[0] + red2[1] + red2[2] + red2[3];
    const float inv = 1.0f / sum;
#pragma unroll
    for (int k = 0; k < 8; k++) {
        const int j = tid + k * 256;
        p[j] = f2bf(v[k] * inv);          // exp(-huge)=0 for masked lanes
    }
}

// ---------- launch ----------
extern "C" void kernel_launch(void* const* d_in, const int* in_sizes, int n_in,
                              void* d_out, int out_size, void* d_ws, size_t ws_size,
                              hipStream_t stream)
{
    const int B = 4, T = 2048, C = 1024, D = 1024;
    const float* x  = (const float*)d_in[0];
    const float* Wq = (const float*)d_in[1];
    const float* Wk = (const float*)d_in[2];
    const float* Wv = (const float*)d_in[3];
    float* out = (float*)d_out;
    char* ws = (char*)d_ws;

    const size_t MB = 1ull << 20;
    // layout (peak 150 MB):
    //  0..16   Xbf        [dead after QKV gemm]
    // 16..22   WqkvT      [dead after QKV gemm]
    // 22..70   QKV (4 x 2048 x 3072 bf16)   [dead after Vt + S]
    // 70..86   Vt  (4 x 1024 x 2048 bf16)
    // 86..150  S   (4 x 2048 x 2048 fp32)
    //  0..32   P   (4 x 2048 x 2048 bf16)   [overlays dead Xbf/WqkvT/QKV-head]
    unsigned short* Xbf   = (unsigned short*)(ws + 0);
    unsigned short* WqkvT = (unsigned short*)(ws + 16 * MB);
    unsigned short* QKV   = (unsigned short*)(ws + 22 * MB);
    unsigned short* Vt    = (unsigned short*)(ws + 70 * MB);
    float*          S     = (float*)(ws + 86 * MB);
    unsigned short* P     = (unsigned short*)(ws + 0);

    const long long sX   = (long long)T * C;
    const long long sQKV = (long long)T * 3 * D;
    const long long sVt  = (long long)D * T;
    const long long sS   = (long long)T * T;
    const long long sO   = (long long)T * D;

    // 1) x -> bf16
    {
        int n4 = B * T * C / 4;
        cast_f32_bf16<<<dim3((n4 + 255) / 256), dim3(256), 0, stream>>>(
            (const float4*)x, Xbf, n4);
    }
    // 2) fused W^T cast
    {
        dim3 g(32, 32, 3), b(32, 8);
        transpose_cast_w3<<<g, b, 0, stream>>>(Wq, Wk, Wv, WqkvT, 1024);
    }
    // 3) fused QKV GEMM: per batch M=2048, N=3072, K=1024
    {
        dim3 g(3072 / 128, 2048 / 128, 4), b(256);
        gemm_bt<unsigned short, false, false><<<g, b, 0, stream>>>(
            Xbf, WqkvT, QKV, 2048, 3072, 1024, 1024, 1024, 3072, sX, 0, sQKV, 1.0f);
    }
    // 4) V (cols 2048..3071 of QKV) -> V^T
    {
        dim3 g(1024 / 32, 2048 / 32, 4), b(32, 8);
        transpose_bf16_k<<<g, b, 0, stream>>>(
            QKV + 2 * D, Vt, 3 * D, T, sQKV, sVt);
    }
    // 5) S = Q K^T / 32, causal lower blocks only
    {
        dim3 g(2048 / 128, 2048 / 128, 4), b(256);
        gemm_bt<float, true, false><<<g, b, 0, stream>>>(
            QKV, QKV + D, S, 2048, 2048, 1024, 3 * D, 3 * D, 2048, sQKV, sQKV, sS, 0.03125f);
    }
    // 6) causal softmax -> P (bf16)
    {
        causal_softmax<<<dim3(B * T), dim3(256), 0, stream>>>(S, P, T);
    }
    // 7) O = P V (K clamped causally per row-block), fp32 out
    {
        dim3 g(1024 / 128, 2048 / 128, 4), b(256);
        gemm_bt<float, false, true><<<g, b, 0, stream>>>(
            P, Vt, out, 2048, 1024, 2048, 2048, 2048, 1024, sS, sVt, sO, 1.0f);
    }
    (void)in_sizes; (void)n_in; (void)out_size; (void)ws_size;
}

// Round 6
// 251.709 us; speedup vs baseline: 1.2075x; 1.0456x over previous
//
#include <hip/hip_runtime.h>
#include <hip/hip_bf16.h>
#include <stdint.h>

// ---------- types ----------
typedef __bf16 bf16x8 __attribute__((ext_vector_type(8)));
typedef float  f32x4  __attribute__((ext_vector_type(4)));
typedef unsigned int u32x4 __attribute__((ext_vector_type(4)));

__device__ __forceinline__ unsigned short f2bf(float x) {
    union { float f; unsigned u; } v; v.f = x;
    unsigned r = v.u + 0x7fffu + ((v.u >> 16) & 1u);   // RNE
    return (unsigned short)(r >> 16);
}

__device__ __forceinline__ float bf2f(unsigned short b) {
    union { unsigned u; float f; } v; v.u = ((unsigned)b) << 16; return v.f;
}

__device__ __forceinline__ void async16(const void* g, void* l) {
    __builtin_amdgcn_global_load_lds(
        (const __attribute__((address_space(1))) void*)g,
        (__attribute__((address_space(3))) void*)l,
        16, 0, 0);
}

// ---------- bf16 B^T GEMM, 128x128 tile, BK=32, 4 waves, DOUBLE-BUFFERED ----------
// A: M x K (row-major bf16 bits, lda), Bt: N x K (row-major, ldb)
// C[m][n] = scale * sum_k A[m][k] * Bt[n][k]
// VFOLD: for n0 >= nsplit the 128x128 output tile is stored TRANSPOSED to
// VtOut (direct from acc; output column is lane-constant) — folds the V->V^T
// transpose into the QKV GEMM epilogue.
// KLIMIT: K clamped causally per row-block; bm reversed so heaviest blocks
// dispatch first (kills the idle tail).
template <typename OutT, bool CAUSAL_SKIP, bool KLIMIT, bool VFOLD>
__global__ __launch_bounds__(256, 3) void gemm_bt(
    const unsigned short* __restrict__ A,
    const unsigned short* __restrict__ Bt,
    OutT* __restrict__ C,
    unsigned short* __restrict__ VtOut,
    int M, int N, int K, int lda, int ldb, int ldc,
    int ldvt, int nsplit,
    long long sA, long long sB, long long sC, long long sVt, float scale)
{
    const int bn = blockIdx.x, bz = blockIdx.z;
    const int bm = KLIMIT ? (gridDim.y - 1 - blockIdx.y) : blockIdx.y;
    if (CAUSAL_SKIP && bn > bm) return;

    A  += (long long)bz * sA;
    Bt += (long long)bz * sB;
    C  += (long long)bz * sC;

    const int m0 = bm * 128, n0 = bn * 128;
    const int Keff = KLIMIT ? min(K, (bm + 1) * 128) : K;

    // [buf][A:128x32 | B:128x32], 16 KB per buffer
    __shared__ __align__(16) unsigned short LDS[2 * 2 * 128 * 32];

    const int tid  = threadIdx.x;
    const int w    = tid >> 6, l = tid & 63;
    const int wr   = w >> 1,  wc = w & 1;
    const int lrow = l & 15,  quad = l >> 4;

    f32x4 acc[4][4] = {};

    // staging: lane l of chunk c covers row 16c + (l>>2); physical k-slot l&3
    // holds logical chunk (l&3)^((l>>3)&3) (row-pair swizzle).
    const int rA0  = 32 * w + (l >> 2);
    const int cOff = (((l & 3) ^ ((l >> 3) & 3))) * 8;
    const unsigned short* aG0 = A  + (long long)(m0 + rA0)      * lda + cOff;
    const unsigned short* aG1 = A  + (long long)(m0 + rA0 + 16) * lda + cOff;
    const unsigned short* bG0 = Bt + (long long)(n0 + rA0)      * ldb + cOff;
    const unsigned short* bG1 = Bt + (long long)(n0 + rA0 + 16) * ldb + cOff;
    unsigned short* aL = &LDS[(2 * w) * 512 + l * 8];           // A region of buf0
    unsigned short* bL = aL + 4096;                             // B region of buf0

    const int sl = (lrow >> 1) & 3;   // un-swizzle for fragment reads

    // prologue: stage tile 0 into buf 0
    async16(aG0, aL);
    async16(aG1, aL + 512);
    async16(bG0, bL);
    async16(bG1, bL + 512);

    for (int k0 = 0; k0 < Keff; k0 += 32) {
        const int cur = ((k0 >> 5) & 1) * 8192;   // element offset of current buf
        __syncthreads();                          // tile k0 ready in cur

        if (k0 + 32 < Keff) {                     // prefetch tile k0+32 into other buf
            const int nxt = cur ^ 8192;
            async16(aG0 + k0 + 32, aL + nxt);
            async16(aG1 + k0 + 32, aL + nxt + 512);
            async16(bG0 + k0 + 32, bL + nxt);
            async16(bG1 + k0 + 32, bL + nxt + 512);
        }

        const unsigned short* As = &LDS[cur];
        const unsigned short* Bs = &LDS[cur + 4096];
        bf16x8 af[4], bfr[4];
#pragma unroll
        for (int i = 0; i < 4; i++) {
            af[i]  = *(const bf16x8*)&As[(wr * 64 + i * 16 + lrow) * 32 + (quad ^ sl) * 8];
            bfr[i] = *(const bf16x8*)&Bs[(wc * 64 + i * 16 + lrow) * 32 + (quad ^ sl) * 8];
        }
#pragma unroll
        for (int i = 0; i < 4; i++)
#pragma unroll
            for (int j = 0; j < 4; j++)
                acc[i][j] = __builtin_amdgcn_mfma_f32_16x16x32_bf16(af[i], bfr[j], acc[i][j], 0, 0, 0);
    }

    // ---- VFOLD: store this tile transposed, straight from acc ----
    if constexpr (VFOLD) {
        if (n0 >= nsplit) {
            unsigned short* Vp = VtOut + (long long)bz * sVt;
#pragma unroll
            for (int i = 0; i < 4; i++) {
                const int t = m0 + wr * 64 + i * 16 + quad * 4;
#pragma unroll
                for (int j = 0; j < 4; j++) {
                    const int d = (n0 - nsplit) + wc * 64 + j * 16 + lrow;
                    union { unsigned short u[4]; uint2 p; } o;
#pragma unroll
                    for (int r = 0; r < 4; r++) o.u[r] = f2bf(acc[i][j][r] * scale);
                    *(uint2*)(Vp + (long long)d * ldvt + t) = o.p;
                }
            }
            return;
        }
    }

    __syncthreads();   // all waves done before LDS is reused for repack

    // ---- epilogue: per-wave LDS repack (16 rows x 144 B stride, 2288 B/wave) ----
    char* eb = (char*)LDS + w * 2288;
    const int erow = l >> 2, ep = l & 3;

    if constexpr (sizeof(OutT) == 2) {
#pragma unroll
        for (int i = 0; i < 4; i++) {
#pragma unroll
            for (int j = 0; j < 4; j++)
#pragma unroll
                for (int r = 0; r < 4; r++)
                    *(unsigned short*)(eb + (quad * 4 + r) * 144 + (j * 16 + lrow) * 2) =
                        f2bf(acc[i][j][r] * scale);
            const long long gm = m0 + wr * 64 + i * 16 + erow;
#pragma unroll
            for (int c = 0; c < 2; c++) {
                u32x4 d = *(u32x4*)(eb + erow * 144 + ep * 32 + c * 16);
                *(u32x4*)((unsigned short*)C + gm * ldc + (n0 + wc * 64 + ep * 16 + c * 8)) = d;
            }
        }
    } else {
#pragma unroll
        for (int i = 0; i < 4; i++) {
            const long long gm = m0 + wr * 64 + i * 16 + erow;
#pragma unroll
            for (int jc = 0; jc < 2; jc++) {
#pragma unroll
                for (int jj = 0; jj < 2; jj++)
#pragma unroll
                    for (int r = 0; r < 4; r++)
                        *(float*)(eb + (quad * 4 + r) * 144 + (jj * 16 + lrow) * 4) =
                            acc[i][2 * jc + jj][r] * scale;
#pragma unroll
                for (int c = 0; c < 2; c++) {
                    f32x4 d = *(f32x4*)(eb + erow * 144 + ep * 32 + c * 16);
                    *(f32x4*)((float*)C + gm * ldc + (n0 + wc * 64 + jc * 32 + ep * 8 + c * 4)) = d;
                }
            }
        }
    }
}

// ---------- fp32 -> bf16 cast (vectorized) ----------
__global__ __launch_bounds__(256) void cast_f32_bf16(
    const float4* __restrict__ in, unsigned short* __restrict__ out, int n4)
{
    int i = blockIdx.x * 256 + threadIdx.x;
    if (i >= n4) return;
    float4 v = in[i];
    union { unsigned short u[4]; uint2 p; } o;
    o.u[0] = f2bf(v.x); o.u[1] = f2bf(v.y); o.u[2] = f2bf(v.z); o.u[3] = f2bf(v.w);
    *(uint2*)(out + (long long)i * 4) = o.p;
}

// ---------- fused W_{q,k,v} (1024x1024 fp32) -> concatenated W^T (3072 x 1024 bf16) ----------
__global__ __launch_bounds__(256) void transpose_cast_w3(
    const float* __restrict__ W0, const float* __restrict__ W1,
    const float* __restrict__ W2, unsigned short* __restrict__ out, int n)
{
    const float* in = (blockIdx.z == 0) ? W0 : (blockIdx.z == 1) ? W1 : W2;
    out += (long long)blockIdx.z * n * n;
    __shared__ float tile[32][33];
    const int tx = threadIdx.x, ty = threadIdx.y;
    const int c0 = blockIdx.x * 32, r0 = blockIdx.y * 32;
#pragma unroll
    for (int i = 0; i < 4; i++)
        tile[ty + i * 8][tx] = in[(long long)(r0 + ty + i * 8) * n + c0 + tx];
    __syncthreads();
#pragma unroll
    for (int i = 0; i < 4; i++)
        out[(long long)(c0 + ty + i * 8) * n + r0 + tx] = f2bf(tile[tx][ty + i * 8]);
}

// ---------- causal softmax: S (bf16, B*T rows of T) -> P (bf16), vectorized ----------
__global__ __launch_bounds__(256) void causal_softmax_bf16(
    const unsigned short* __restrict__ S, unsigned short* __restrict__ P, int T)
{
    const int row = blockIdx.x;            // 0 .. B*T-1
    const int t   = row & (T - 1);
    const int L   = t + 1;
    const unsigned short* s = S + (long long)row * T;
    unsigned short* p = P + (long long)row * T;
    const int tid  = threadIdx.x;
    const int base = tid * 8;

    uint4 raw = *(const uint4*)(s + base);
    unsigned rr[4] = {raw.x, raw.y, raw.z, raw.w};
    float v[8];
#pragma unroll
    for (int k = 0; k < 4; k++) {
        union { unsigned u; float f; } a, b;
        a.u = (rr[k] & 0xFFFFu) << 16;
        b.u = rr[k] & 0xFFFF0000u;
        v[2 * k] = a.f; v[2 * k + 1] = b.f;
    }
    float mx = -3.0e38f;
#pragma unroll
    for (int k = 0; k < 8; k++) {
        if (base + k >= L) v[k] = -3.0e38f;
        mx = fmaxf(mx, v[k]);
    }
#pragma unroll
    for (int off = 32; off; off >>= 1) mx = fmaxf(mx, __shfl_xor(mx, off));
    __shared__ float red[4], red2[4];
    const int wid = tid >> 6, lid = tid & 63;
    if (lid == 0) red[wid] = mx;
    __syncthreads();
    mx = fmaxf(fmaxf(red[0], red[1]), fmaxf(red[2], red[3]));

    float sum = 0.f;
#pragma unroll
    for (int k = 0; k < 8; k++) { v[k] = __expf(v[k] - mx); sum += v[k]; }
#pragma unroll
    for (int off = 32; off; off >>= 1) sum += __shfl_xor(sum, off);
    if (lid == 0) red2[wid] = sum;
    __syncthreads();
    sum = red2[0] + red2[1] + red2[2] + red2[3];
    const float inv = 1.0f / sum;

    union { unsigned short u[8]; uint4 q; } o;
#pragma unroll
    for (int k = 0; k < 8; k++) o.u[k] = f2bf(v[k] * inv);
    *(uint4*)(p + base) = o.q;
}

// ---------- launch ----------
extern "C" void kernel_launch(void* const* d_in, const int* in_sizes, int n_in,
                              void* d_out, int out_size, void* d_ws, size_t ws_size,
                              hipStream_t stream)
{
    const int B = 4, T = 2048, C = 1024, D = 1024;
    const float* x  = (const float*)d_in[0];
    const float* Wq = (const float*)d_in[1];
    const float* Wk = (const float*)d_in[2];
    const float* Wv = (const float*)d_in[3];
    float* out = (float*)d_out;
    char* ws = (char*)d_ws;

    const size_t MB = 1ull << 20;
    // layout (peak 102 MB):
    //  0..16   Xbf          [dead after QKV gemm]
    // 16..22   WqkvT        [dead after QKV gemm]
    // 22..54   QK  (4 x 2048 x 2048 bf16: Q cols 0..1023, K cols 1024..2047)
    // 54..70   Vt  (4 x 1024 x 2048 bf16, written by QKV epilogue VFOLD)
    // 70..102  Sbf (4 x 2048 x 2048 bf16)
    //  0..32   P   (4 x 2048 x 2048 bf16) [overlays dead Xbf/WqkvT/QK-head]
    unsigned short* Xbf   = (unsigned short*)(ws + 0);
    unsigned short* WqkvT = (unsigned short*)(ws + 16 * MB);
    unsigned short* QK    = (unsigned short*)(ws + 22 * MB);
    unsigned short* Vt    = (unsigned short*)(ws + 54 * MB);
    unsigned short* Sbf   = (unsigned short*)(ws + 70 * MB);
    unsigned short* P     = (unsigned short*)(ws + 0);

    const long long sX  = (long long)T * C;        // 2048*1024
    const long long sQK = (long long)T * 2 * D;    // 2048*2048
    const long long sVt = (long long)D * T;        // 1024*2048
    const long long sS  = (long long)T * T;        // 2048*2048
    const long long sO  = (long long)T * D;        // 2048*1024

    // 1) x -> bf16
    {
        int n4 = B * T * C / 4;
        cast_f32_bf16<<<dim3((n4 + 255) / 256), dim3(256), 0, stream>>>(
            (const float4*)x, Xbf, n4);
    }
    // 2) fused W^T cast
    {
        dim3 g(32, 32, 3), b(32, 8);
        transpose_cast_w3<<<g, b, 0, stream>>>(Wq, Wk, Wv, WqkvT, 1024);
    }
    // 3) fused QKV GEMM: Q,K -> QK (ldc 2048); V third -> Vt transposed (VFOLD)
    {
        dim3 g(3072 / 128, 2048 / 128, 4), b(256);
        gemm_bt<unsigned short, false, false, true><<<g, b, 0, stream>>>(
            Xbf, WqkvT, QK, Vt, 2048, 3072, 1024, 1024, 1024, 2048,
            /*ldvt*/ T, /*nsplit*/ 2048, sX, 0, sQK, sVt, 1.0f);
    }
    // 4) S = Q K^T / 32 -> bf16, causal lower blocks only
    {
        dim3 g(2048 / 128, 2048 / 128, 4), b(256);
        gemm_bt<unsigned short, true, false, false><<<g, b, 0, stream>>>(
            QK, QK + D, Sbf, nullptr, 2048, 2048, 1024, 2 * D, 2 * D, 2048,
            0, 0, sQK, sQK, sS, 0, 0.03125f);
    }
    // 5) causal softmax (bf16 -> bf16)
    {
        causal_softmax_bf16<<<dim3(B * T), dim3(256), 0, stream>>>(Sbf, P, T);
    }
    // 6) O = P V (K clamped causally, heavy row-blocks dispatched first), fp32 out
    {
        dim3 g(1024 / 128, 2048 / 128, 4), b(256);
        gemm_bt<float, false, true, false><<<g, b, 0, stream>>>(
            P, Vt, out, nullptr, 2048, 1024, 2048, 2048, 2048, 1024,
            0, 0, sS, sVt, sO, 0, 1.0f);
    }
    (void)in_sizes; (void)n_in; (void)out_size; (void)ws_size;
}